// Round 20
// baseline (183.551 us; speedup 1.0000x reference)
//
#include <hip/hip_runtime.h>
#include <hip/hip_bf16.h>

#define N_NODES 8192
#define E_EDGES 262144
#define HID 128
#define FIN 256
#define CAP 128  // fixed CSR bin capacity; deg ~ Binom(262144,1/8192), max ~60

typedef __attribute__((ext_vector_type(8))) short bf16x8;
typedef __attribute__((ext_vector_type(4))) float f32x4;

// ---- h = X @ W (fp32 vector). 16 rows/block. Also zeroes cursor (runs first). ----
__global__ __launch_bounds__(256) void xw_kernel(const float* __restrict__ x,
                                                 const float* __restrict__ W,
                                                 float* __restrict__ h,
                                                 unsigned* __restrict__ cursor) {
    if (blockIdx.x < 32) cursor[blockIdx.x * 256 + threadIdx.x] = 0u;

    int col = threadIdx.x & 127;
    int row0 = blockIdx.x * 16 + (threadIdx.x >> 7) * 8;
    const float* xr = x + (size_t)row0 * FIN;
    float acc[8];
#pragma unroll
    for (int r = 0; r < 8; ++r) acc[r] = 0.f;

    for (int k = 0; k < FIN; k += 4) {
        float4 xv[8];
#pragma unroll
        for (int r = 0; r < 8; ++r) xv[r] = *(const float4*)(xr + r * FIN + k);
#pragma unroll
        for (int kk = 0; kk < 4; ++kk) {
            float w = W[(size_t)(k + kk) * HID + col];
#pragma unroll
            for (int r = 0; r < 8; ++r)
                acc[r] = fmaf(((const float*)&xv[r])[kk], w, acc[r]);
        }
    }
#pragma unroll
    for (int r = 0; r < 8; ++r)
        h[(size_t)(row0 + r) * HID + col] = acc[r];
}

// ---- scatter edges into fixed-capacity CSR bins (by dst); cursor ends as deg count ----
__global__ void scatter_csr(const int* __restrict__ src, const int* __restrict__ dst,
                            unsigned* __restrict__ cursor, int* __restrict__ csr_src) {
    int e = blockIdx.x * 256 + threadIdx.x;
    if (e < E_EDGES) {
        int d = dst[e];
        unsigned pos = atomicAdd(&cursor[d], 1u);
        csr_src[(size_t)d * CAP + pos] = src[e];
    }
}

// ---- sym-normalized aggregation + bias + relu (r15 ILP form). ----
__global__ __launch_bounds__(256) void agg_kernel(const float* __restrict__ h,
                                                  const unsigned* __restrict__ cnt,
                                                  const int* __restrict__ csr_src,
                                                  const float* __restrict__ b,
                                                  float* __restrict__ z_out,
                                                  __hip_bfloat16* __restrict__ zb) {
    int row = blockIdx.x;
    int slot = threadIdx.x >> 6;  // 0..3 (wave id)
    int fp = threadIdx.x & 63;    // feature pair index
    const float2* h2 = (const float2*)h;
    const int* bin = csr_src + (size_t)row * CAP;

    unsigned ne = cnt[row];
    float ax = 0.f, ay = 0.f;
    for (unsigned base = (unsigned)slot * 8; base < ne; base += 32) {
        int4 i0 = *(const int4*)(bin + base);
        int4 i1 = *(const int4*)(bin + base + 4);
        int ss[8] = {i0.x, i0.y, i0.z, i0.w, i1.x, i1.y, i1.z, i1.w};
        unsigned rem = ne - base;  // >= 1
#pragma unroll
        for (int j = 0; j < 8; ++j) {
            int s = ((unsigned)j < rem) ? ss[j] : ss[0];  // clamp: always valid
            float ds = rsqrtf((float)(cnt[s] + 1u));
            ds = ((unsigned)j < rem) ? ds : 0.f;          // tail contributes 0
            float2 hv = h2[(size_t)s * 64 + fp];          // independent loads
            ax = fmaf(hv.x, ds, ax);
            ay = fmaf(hv.y, ds, ay);
        }
    }
    __shared__ float part[4][64][2];
    part[slot][fp][0] = ax;
    part[slot][fp][1] = ay;
    __syncthreads();
    if (slot == 0) {
        float di = rsqrtf((float)(ne + 1u));
        float2 hv = h2[(size_t)row * 64 + fp];
        float sx = (part[0][fp][0] + part[1][fp][0]) + (part[2][fp][0] + part[3][fp][0]) + hv.x * di;
        float sy = (part[0][fp][1] + part[1][fp][1]) + (part[2][fp][1] + part[3][fp][1]) + hv.y * di;
        float2 bb = ((const float2*)b)[fp];
        float zx = fmaxf(fmaf(sx, di, bb.x), 0.f);
        float zy = fmaxf(fmaf(sy, di, bb.y), 0.f);
        ((float2*)z_out)[(size_t)row * 64 + fp] = make_float2(zx, zy);
        unsigned short bx = __builtin_bit_cast(unsigned short, __float2bfloat16(zx));
        unsigned short by = __builtin_bit_cast(unsigned short, __float2bfloat16(zy));
        ((unsigned*)zb)[(size_t)row * 64 + fp] = ((unsigned)by << 16) | (unsigned)bx;
    }
}

// ---- adj = sigmoid(z @ z^T): r18 form (r15 geometry + nt mirror). ----
__global__ __launch_bounds__(256) void gemm_sig(const __hip_bfloat16* __restrict__ zb,
                                                float* __restrict__ adj) {
    int strip = blockIdx.x & 7;
    int p = blockIdx.x >> 3;  // 0..135 triangular pair index
    int TI = 0, rem = p;
    while (rem >= 16 - TI) { rem -= 16 - TI; ++TI; }
    int TJ = TI + rem;

    int wid = threadIdx.x >> 6;
    int lane = threadIdx.x & 63;
    int lr = lane & 15;  // fragment index
    int hi = lane >> 4;  // 0..3
    int lk = hi * 8;     // k sub-offset

    int row0 = TI * 512 + strip * 64;  // adj rows (A = z rows)
    int col0 = TJ * 512 + wid * 128;   // adj cols (B = z rows)

    f32x4 acc[4][8];
#pragma unroll
    for (int m = 0; m < 4; ++m)
#pragma unroll
        for (int n = 0; n < 8; ++n) acc[m][n] = (f32x4){0.f, 0.f, 0.f, 0.f};

#pragma unroll
    for (int ks = 0; ks < 4; ++ks) {
        int k = ks * 32 + lk;
        bf16x8 a[4], bfr[8];
#pragma unroll
        for (int m = 0; m < 4; ++m)
            a[m] = *(const bf16x8*)(zb + (size_t)(row0 + m * 16 + lr) * HID + k);
#pragma unroll
        for (int n = 0; n < 8; ++n)
            bfr[n] = *(const bf16x8*)(zb + (size_t)(col0 + n * 16 + lr) * HID + k);
#pragma unroll
        for (int m = 0; m < 4; ++m)
#pragma unroll
            for (int n = 0; n < 8; ++n)
                acc[m][n] = __builtin_amdgcn_mfma_f32_16x16x32_bf16(a[m], bfr[n], acc[m][n], 0, 0, 0);
    }

    int orow = hi * 4;
    bool mirror = (TI != TJ);
#pragma unroll
    for (int m = 0; m < 4; ++m) {
        int rowb = row0 + m * 16 + orow;  // multiple of 4
#pragma unroll
        for (int n = 0; n < 8; ++n) {
            int col = col0 + n * 16 + lr;
            f32x4 s4;
#pragma unroll
            for (int r = 0; r < 4; ++r) {
                float v = acc[m][n][r];
                s4[r] = __builtin_amdgcn_rcpf(1.0f + __expf(-v));
            }
            // primary row-major: 2KB runs per adj-row.
#pragma unroll
            for (int r = 0; r < 4; ++r)
                adj[(size_t)(rowb + r) * N_NODES + col] = s4[r];
            // mirror: float4 full-line nt stores at adj[col][row].
            if (mirror)
                __builtin_nontemporal_store(s4, (f32x4*)(adj + (size_t)col * N_NODES + rowb));
        }
    }
}

extern "C" void kernel_launch(void* const* d_in, const int* in_sizes, int n_in,
                              void* d_out, int out_size, void* d_ws, size_t ws_size,
                              hipStream_t stream) {
    const float* x = (const float*)d_in[0];
    const int* ei = (const int*)d_in[1];
    const float* W = (const float*)d_in[2];
    const float* b = (const float*)d_in[3];
    const int* src = ei;
    const int* dst = ei + E_EDGES;

    float* adj = (float*)d_out;
    float* z_out = (float*)d_out + (size_t)N_NODES * N_NODES;

    char* ws = (char*)d_ws;
    float* h = (float*)ws;                                    // 4 MB
    __hip_bfloat16* zb = (__hip_bfloat16*)(ws + (4u << 20));  // 2 MB
    unsigned* cursor = (unsigned*)(ws + (6u << 20));          // 32 KB
    int* csr = (int*)(ws + (6u << 20) + (32u << 10));         // 4 MB (8192*128*4)

    // ATTRIBUTION: extra (xw, scatter) pair — jointly idempotent (xw re-zeroes
    // cursor + rewrites identical h; scatter re-fills same bin contents).
    // T20 - 134.5 = xw + scatter (+2 boundaries).
    hipLaunchKernelGGL(xw_kernel, dim3(N_NODES / 16), dim3(256), 0, stream, x, W, h, cursor);
    hipLaunchKernelGGL(scatter_csr, dim3(E_EDGES / 256), dim3(256), 0, stream, src, dst, cursor, csr);
    hipLaunchKernelGGL(xw_kernel, dim3(N_NODES / 16), dim3(256), 0, stream, x, W, h, cursor);
    hipLaunchKernelGGL(scatter_csr, dim3(E_EDGES / 256), dim3(256), 0, stream, src, dst, cursor, csr);
    hipLaunchKernelGGL(agg_kernel, dim3(N_NODES), dim3(256), 0, stream, h, cursor, csr, b, z_out, zb);
    hipLaunchKernelGGL(gemm_sig, dim3(136 * 8), dim3(256), 0, stream, zb, adj);
}

// Round 21
// 133.833 us; speedup vs baseline: 1.3715x; 1.3715x over previous
//
#include <hip/hip_runtime.h>
#include <hip/hip_bf16.h>

#define N_NODES 8192
#define E_EDGES 262144
#define HID 128
#define FIN 256
#define CAP 128   // fixed CSR bin capacity; deg ~ Binom(262144,1/8192), max ~60
#define CSTRIDE 16  // cursor counter stride (uints): 1 counter per 64B line

typedef __attribute__((ext_vector_type(8))) short bf16x8;
typedef __attribute__((ext_vector_type(4))) float f32x4;

// ---- h = X @ W (fp32 vector). 16 rows/block. Also zeroes cursor (runs first).
// cursor is now 8192*16 uints (512KB, 1 counter/64B line): every block zeroes
// 256 entries -> 512*256 = 131072 = full coverage. ----
__global__ __launch_bounds__(256) void xw_kernel(const float* __restrict__ x,
                                                 const float* __restrict__ W,
                                                 float* __restrict__ h,
                                                 unsigned* __restrict__ cursor) {
    cursor[blockIdx.x * 256 + threadIdx.x] = 0u;

    int col = threadIdx.x & 127;
    int row0 = blockIdx.x * 16 + (threadIdx.x >> 7) * 8;
    const float* xr = x + (size_t)row0 * FIN;
    float acc[8];
#pragma unroll
    for (int r = 0; r < 8; ++r) acc[r] = 0.f;

    for (int k = 0; k < FIN; k += 4) {
        float4 xv[8];
#pragma unroll
        for (int r = 0; r < 8; ++r) xv[r] = *(const float4*)(xr + r * FIN + k);
#pragma unroll
        for (int kk = 0; kk < 4; ++kk) {
            float w = W[(size_t)(k + kk) * HID + col];
#pragma unroll
            for (int r = 0; r < 8; ++r)
                acc[r] = fmaf(((const float*)&xv[r])[kk], w, acc[r]);
        }
    }
#pragma unroll
    for (int r = 0; r < 8; ++r)
        h[(size_t)(row0 + r) * HID + col] = acc[r];
}

// ---- scatter edges into fixed-capacity CSR bins (by dst).
// Counter padded to one per 64B line: same-line atomic queues drop from
// 512 deep (16 counters/line x 32 ops) to 32 deep (true same-address only). ----
__global__ void scatter_csr(const int* __restrict__ src, const int* __restrict__ dst,
                            unsigned* __restrict__ cursor, int* __restrict__ csr_src) {
    int e = blockIdx.x * 256 + threadIdx.x;
    if (e < E_EDGES) {
        int d = dst[e];
        unsigned pos = atomicAdd(&cursor[(size_t)d * CSTRIDE], 1u);
        csr_src[(size_t)d * CAP + pos] = src[e];
    }
}

// ---- sym-normalized aggregation + bias + relu (r15 ILP form; cnt stride 16). ----
__global__ __launch_bounds__(256) void agg_kernel(const float* __restrict__ h,
                                                  const unsigned* __restrict__ cnt,
                                                  const int* __restrict__ csr_src,
                                                  const float* __restrict__ b,
                                                  float* __restrict__ z_out,
                                                  __hip_bfloat16* __restrict__ zb) {
    int row = blockIdx.x;
    int slot = threadIdx.x >> 6;  // 0..3 (wave id)
    int fp = threadIdx.x & 63;    // feature pair index
    const float2* h2 = (const float2*)h;
    const int* bin = csr_src + (size_t)row * CAP;

    unsigned ne = cnt[(size_t)row * CSTRIDE];
    float ax = 0.f, ay = 0.f;
    for (unsigned base = (unsigned)slot * 8; base < ne; base += 32) {
        int4 i0 = *(const int4*)(bin + base);
        int4 i1 = *(const int4*)(bin + base + 4);
        int ss[8] = {i0.x, i0.y, i0.z, i0.w, i1.x, i1.y, i1.z, i1.w};
        unsigned rem = ne - base;  // >= 1
#pragma unroll
        for (int j = 0; j < 8; ++j) {
            int s = ((unsigned)j < rem) ? ss[j] : ss[0];  // clamp: always valid
            float ds = rsqrtf((float)(cnt[(size_t)s * CSTRIDE] + 1u));
            ds = ((unsigned)j < rem) ? ds : 0.f;          // tail contributes 0
            float2 hv = h2[(size_t)s * 64 + fp];          // independent loads
            ax = fmaf(hv.x, ds, ax);
            ay = fmaf(hv.y, ds, ay);
        }
    }
    __shared__ float part[4][64][2];
    part[slot][fp][0] = ax;
    part[slot][fp][1] = ay;
    __syncthreads();
    if (slot == 0) {
        float di = rsqrtf((float)(ne + 1u));
        float2 hv = h2[(size_t)row * 64 + fp];
        float sx = (part[0][fp][0] + part[1][fp][0]) + (part[2][fp][0] + part[3][fp][0]) + hv.x * di;
        float sy = (part[0][fp][1] + part[1][fp][1]) + (part[2][fp][1] + part[3][fp][1]) + hv.y * di;
        float2 bb = ((const float2*)b)[fp];
        float zx = fmaxf(fmaf(sx, di, bb.x), 0.f);
        float zy = fmaxf(fmaf(sy, di, bb.y), 0.f);
        ((float2*)z_out)[(size_t)row * 64 + fp] = make_float2(zx, zy);
        unsigned short bx = __builtin_bit_cast(unsigned short, __float2bfloat16(zx));
        unsigned short by = __builtin_bit_cast(unsigned short, __float2bfloat16(zy));
        ((unsigned*)zb)[(size_t)row * 64 + fp] = ((unsigned)by << 16) | (unsigned)bx;
    }
}

// ---- adj = sigmoid(z @ z^T): r18 form (r15 geometry + nt mirror). ----
__global__ __launch_bounds__(256) void gemm_sig(const __hip_bfloat16* __restrict__ zb,
                                                float* __restrict__ adj) {
    int strip = blockIdx.x & 7;
    int p = blockIdx.x >> 3;  // 0..135 triangular pair index
    int TI = 0, rem = p;
    while (rem >= 16 - TI) { rem -= 16 - TI; ++TI; }
    int TJ = TI + rem;

    int wid = threadIdx.x >> 6;
    int lane = threadIdx.x & 63;
    int lr = lane & 15;  // fragment index
    int hi = lane >> 4;  // 0..3
    int lk = hi * 8;     // k sub-offset

    int row0 = TI * 512 + strip * 64;  // adj rows (A = z rows)
    int col0 = TJ * 512 + wid * 128;   // adj cols (B = z rows)

    f32x4 acc[4][8];
#pragma unroll
    for (int m = 0; m < 4; ++m)
#pragma unroll
        for (int n = 0; n < 8; ++n) acc[m][n] = (f32x4){0.f, 0.f, 0.f, 0.f};

#pragma unroll
    for (int ks = 0; ks < 4; ++ks) {
        int k = ks * 32 + lk;
        bf16x8 a[4], bfr[8];
#pragma unroll
        for (int m = 0; m < 4; ++m)
            a[m] = *(const bf16x8*)(zb + (size_t)(row0 + m * 16 + lr) * HID + k);
#pragma unroll
        for (int n = 0; n < 8; ++n)
            bfr[n] = *(const bf16x8*)(zb + (size_t)(col0 + n * 16 + lr) * HID + k);
#pragma unroll
        for (int m = 0; m < 4; ++m)
#pragma unroll
            for (int n = 0; n < 8; ++n)
                acc[m][n] = __builtin_amdgcn_mfma_f32_16x16x32_bf16(a[m], bfr[n], acc[m][n], 0, 0, 0);
    }

    int orow = hi * 4;
    bool mirror = (TI != TJ);
#pragma unroll
    for (int m = 0; m < 4; ++m) {
        int rowb = row0 + m * 16 + orow;  // multiple of 4
#pragma unroll
        for (int n = 0; n < 8; ++n) {
            int col = col0 + n * 16 + lr;
            f32x4 s4;
#pragma unroll
            for (int r = 0; r < 4; ++r) {
                float v = acc[m][n][r];
                s4[r] = __builtin_amdgcn_rcpf(1.0f + __expf(-v));
            }
            // primary row-major: 2KB runs per adj-row.
#pragma unroll
            for (int r = 0; r < 4; ++r)
                adj[(size_t)(rowb + r) * N_NODES + col] = s4[r];
            // mirror: float4 full-line nt stores at adj[col][row].
            if (mirror)
                __builtin_nontemporal_store(s4, (f32x4*)(adj + (size_t)col * N_NODES + rowb));
        }
    }
}

extern "C" void kernel_launch(void* const* d_in, const int* in_sizes, int n_in,
                              void* d_out, int out_size, void* d_ws, size_t ws_size,
                              hipStream_t stream) {
    const float* x = (const float*)d_in[0];
    const int* ei = (const int*)d_in[1];
    const float* W = (const float*)d_in[2];
    const float* b = (const float*)d_in[3];
    const int* src = ei;
    const int* dst = ei + E_EDGES;

    float* adj = (float*)d_out;
    float* z_out = (float*)d_out + (size_t)N_NODES * N_NODES;

    char* ws = (char*)d_ws;
    float* h = (float*)ws;                                        // 4 MB
    __hip_bfloat16* zb = (__hip_bfloat16*)(ws + (4u << 20));      // 2 MB
    unsigned* cursor = (unsigned*)(ws + (6u << 20));              // 512 KB (padded)
    int* csr = (int*)(ws + (6u << 20) + (512u << 10));            // 4 MB (8192*128*4)

    // xw first: independent of edges, also zeroes cursor for scatter.
    hipLaunchKernelGGL(xw_kernel, dim3(N_NODES / 16), dim3(256), 0, stream, x, W, h, cursor);
    hipLaunchKernelGGL(scatter_csr, dim3(E_EDGES / 256), dim3(256), 0, stream, src, dst, cursor, csr);
    hipLaunchKernelGGL(agg_kernel, dim3(N_NODES), dim3(256), 0, stream, h, cursor, csr, b, z_out, zb);
    hipLaunchKernelGGL(gemm_sig, dim3(136 * 8), dim3(256), 0, stream, zb, adj);
}